// Round 12
// baseline (328.842 us; speedup 1.0000x reference)
//
#include <hip/hip_runtime.h>
#include <math.h>

#define CDIM 8192
#define DDIM 512
#define NEGF -3.0e38f
#define POSF  3.0e38f

#define BM 128
#define NSLOT (CDIM / BM) /* 64 col-slots of 128 per row */

typedef __attribute__((ext_vector_type(8))) short bf16x8;
typedef __attribute__((ext_vector_type(4))) float f32x4;

__device__ __forceinline__ unsigned short f2bf(float x) {
    unsigned int u = __float_as_uint(x);
    u += 0x7fffu + ((u >> 16) & 1u);
    return (unsigned short)(u >> 16);
}
__device__ __forceinline__ float bf2f(unsigned short h) {
    return __uint_as_float(((unsigned int)h) << 16);
}
// async global->LDS, 16B per lane. LDS dest is wave-uniform base + lane*16.
__device__ __forceinline__ void gld16(const void* g, void* l) {
    __builtin_amdgcn_global_load_lds(
        (__attribute__((address_space(1))) void*)(void*)g,
        (__attribute__((address_space(3))) void*)l, 16, 0, 0);
}

// ---- k_prep: normalize rows of G, split into bf16 hi/lo ----
__global__ __launch_bounds__(256) void k_prep(const float* __restrict__ g,
                                              unsigned short* __restrict__ hi,
                                              unsigned short* __restrict__ lo) {
    const int wave = threadIdx.x >> 6;
    const int lane = threadIdx.x & 63;
    const int row = blockIdx.x * 4 + wave;
    const float4* src = (const float4*)(g + (size_t)row * DDIM);
    const float4 a = src[lane * 2];
    const float4 b = src[lane * 2 + 1];
    float s = a.x * a.x + a.y * a.y + a.z * a.z + a.w * a.w +
              b.x * b.x + b.y * b.y + b.z * b.z + b.w * b.w;
#pragma unroll
    for (int m = 1; m < 64; m <<= 1) s += __shfl_xor(s, m, 64);
    const float rn = rsqrtf(s);
    const float y[8] = {a.x * rn, a.y * rn, a.z * rn, a.w * rn,
                        b.x * rn, b.y * rn, b.z * rn, b.w * rn};
    unsigned int hv[4], lv[4];
#pragma unroll
    for (int i = 0; i < 4; ++i) {
        const unsigned short h0 = f2bf(y[2 * i]);
        const unsigned short h1 = f2bf(y[2 * i + 1]);
        const unsigned short l0 = f2bf(y[2 * i] - bf2f(h0));
        const unsigned short l1 = f2bf(y[2 * i + 1] - bf2f(h1));
        hv[i] = (unsigned int)h0 | ((unsigned int)h1 << 16);
        lv[i] = (unsigned int)l0 | ((unsigned int)l1 << 16);
    }
    uint4* dh = (uint4*)(hi + (size_t)row * DDIM + lane * 8);
    uint4* dl = (uint4*)(lo + (size_t)row * DDIM + lane * 8);
    *dh = make_uint4(hv[0], hv[1], hv[2], hv[3]);
    *dl = make_uint4(lv[0], lv[1], lv[2], lv[3]);
}

// Off-diag super-tile assignment table: code = SI*8+SJ (SI<SJ, 8x8 super
// grid over the 64x64 tile grid). XCD0-3: 3 supers each (idx xcd*3+sup);
// XCD4-7: 4 supers each (idx 12+(xcd-4)*4+sup). Greedy-balanced:
// XCD0-3 also carry 2 diagonal supers (36 tiles) -> 264 tiles; XCD4-7: 256.
__device__ __constant__ unsigned char OSUP[28] = {
    1, 2, 10,   3, 11, 19,   4, 12, 20,   28, 5, 13,
    21, 29, 37, 6,   14, 22, 30, 38,   46, 7, 15, 23,   31, 39, 47, 55};

// ---- k_simstats: symmetric, L2 super-tiled, co-staged, BK=32, 32KB LDS ----
// Fixed-reference softmax: Zref = sum exp(S-1) (S in [-1,1] -> exp in
// [.135,1]: no overflow/underflow, partials add plainly).
// 2112 blocks; bid%8 = XCD; each XCD owns whole 8x8 super-tiles (I fastest
// within a super: B-tile shared x8, super's A+B bands L2-resident).
// 128x128 tile, 4 waves 2x2, rt4 x ct4 16x16x32 frags; per K-chunk (BK=32)
// stage Ahi|Alo|Bhi|Blo (32 KB) and run hi*hi+hi*lo+lo*hi.
// launch_bounds (256,4): 64 arch + 64 acc = 128 unified regs -> 4 waves/EU
// legal; LDS 32KB allows 5 blocks/CU -> occupancy target 4 blocks/CU.
// Strict-upper tiles also emit col stats (mirror rows, S=S^T). Slot p of row
// i covers cols [p*128,(p+1)*128): row-stats->slot J, col-stats->slot I.
// Cross-lane merges: strict >/< without index tie-break (exact fp32 ties
// across lanes measure-zero; in-lane scan order preserves first-occurrence).
__global__ __launch_bounds__(256, 4) void k_simstats(
    const unsigned short* __restrict__ ghi, const unsigned short* __restrict__ glo,
    float* __restrict__ pmax, float* __restrict__ pmin, float* __restrict__ pZ,
    int* __restrict__ pamax, int* __restrict__ pamin) {
    // ---- tile mapping (block-uniform) ----
    const int bid = blockIdx.x;
    const int xcd = bid & 7;
    const int off = bid >> 3;
    int I, J;
    if (xcd < 4) {
        if (off < 72) {  // two diagonal supers: s = xcd*2 + (off>=36)
            const int s = xcd * 2 + (off >= 36);
            const int u = (off >= 36) ? off - 36 : off;
            int jj = 0;  // triangular: i<=j within the 8x8 super, i fastest
            while ((jj + 1) * (jj + 2) / 2 <= u) ++jj;
            const int ii = u - jj * (jj + 1) / 2;
            I = s * 8 + ii; J = s * 8 + jj;
        } else {
            const int sup = (off - 72) >> 6;
            const int u = (off - 72) & 63;
            const int code = OSUP[xcd * 3 + sup];
            I = (code >> 3) * 8 + (u & 7);   // I fastest: B-tile shared x8
            J = (code & 7) * 8 + (u >> 3);
        }
    } else {
        if (off >= 256) return;  // 32 pad blocks
        const int sup = off >> 6;
        const int u = off & 63;
        const int code = OSUP[12 + (xcd - 4) * 4 + sup];
        I = (code >> 3) * 8 + (u & 7);
        J = (code & 7) * 8 + (u >> 3);
    }

    __shared__ unsigned short SH[4 * BM * 32];  // 32 KB: Ahi|Alo|Bhi|Blo
    unsigned short* Ahi = SH;
    unsigned short* Alo = SH + 4096;
    unsigned short* Bhi = SH + 8192;
    unsigned short* Blo = SH + 12288;
    const int t = threadIdx.x;
    const int wave = t >> 6;
    const int lane = t & 63;
    const int lanelo = lane & 15;
    const int quad = lane >> 4;
    const int wr = wave & 1;
    const int wc = wave >> 1;

    // staging: per region thread t fills slots t*16 + q*4096 ->
    // (row = (t>>2)+64q, chunk-slot = t&3); src chunk = slot ^ ((row>>1)&3)
    const int srow = t >> 2;                             // 0..63
    const int scolb = ((t & 3) ^ ((t >> 3) & 3)) << 4;   // swizzled src chunk
    char* lAh = (char*)Ahi + t * 16;
    char* lAl = (char*)Alo + t * 16;
    char* lBh = (char*)Bhi + t * 16;
    char* lBl = (char*)Blo + t * 16;

    // frag-read slot (ushort units): quad ^ ((lanelo>>1)&3), loop-invariant
    const int fsl = (quad ^ ((lanelo >> 1) & 3)) << 3;
    const int aoff = (wr * 64 + lanelo) * 32 + fsl;  // + rt*16*32
    const int boff = (wc * 64 + lanelo) * 32 + fsl;  // + ct*16*32

    // epilogue LDS overlays (A half: row stats; B half: col stats)
    float* rm  = (float*)SH;            // [2 wc][128]
    float* rz  = rm + 256;
    float* rmn = rz + 256;
    int*   ra  = (int*)(rmn + 256);
    int*   ran = ra + 256;              // 5 KB < 8 KB (Ahi+Alo)
    float* cm  = (float*)Bhi;           // [2 wr][128]
    float* cz  = cm + 256;
    float* cmn = cz + 256;
    int*   ca  = (int*)(cmn + 256);
    int*   can = ca + 256;

    const int i0 = I * BM;
    const int j0 = J * BM;
    const bool isdiag = (I == J);

    f32x4 acc[4][4];
#pragma unroll
    for (int rt = 0; rt < 4; ++rt)
#pragma unroll
        for (int ct = 0; ct < 4; ++ct)
            acc[rt][ct] = (f32x4){0.f, 0.f, 0.f, 0.f};

    const char* baseAh = (const char*)ghi + (size_t)(i0 + srow) * 1024 + scolb;
    const char* baseAl = (const char*)glo + (size_t)(i0 + srow) * 1024 + scolb;
    const char* baseBh = (const char*)ghi + (size_t)(j0 + srow) * 1024 + scolb;
    const char* baseBl = (const char*)glo + (size_t)(j0 + srow) * 1024 + scolb;

    for (int k0 = 0; k0 < DDIM; k0 += 32) {
        __syncthreads();  // prior frag/epilogue LDS reads done
#pragma unroll
        for (int q = 0; q < 2; ++q) {
            const size_t roff = (size_t)q * 64 * 1024 + k0 * 2;
            gld16(baseAh + roff, lAh + q * 4096);
            gld16(baseAl + roff, lAl + q * 4096);
            gld16(baseBh + roff, lBh + q * 4096);
            gld16(baseBl + roff, lBl + q * 4096);
        }
        __syncthreads();  // drains vmcnt: staged data visible
        bf16x8 ah[4], al[4];
#pragma unroll
        for (int rt = 0; rt < 4; ++rt) {
            ah[rt] = *(const bf16x8*)&Ahi[aoff + rt * 512];
            al[rt] = *(const bf16x8*)&Alo[aoff + rt * 512];
        }
#pragma unroll
        for (int ct = 0; ct < 4; ++ct) {
            const bf16x8 bh = *(const bf16x8*)&Bhi[boff + ct * 512];
            const bf16x8 bl = *(const bf16x8*)&Blo[boff + ct * 512];
#pragma unroll
            for (int rt = 0; rt < 4; ++rt) {
                acc[rt][ct] = __builtin_amdgcn_mfma_f32_16x16x32_bf16(
                    ah[rt], bh, acc[rt][ct], 0, 0, 0);
                acc[rt][ct] = __builtin_amdgcn_mfma_f32_16x16x32_bf16(
                    ah[rt], bl, acc[rt][ct], 0, 0, 0);
                acc[rt][ct] = __builtin_amdgcn_mfma_f32_16x16x32_bf16(
                    al[rt], bh, acc[rt][ct], 0, 0, 0);
            }
        }
    }

    __syncthreads();  // all frag reads done before LDS overlay

    // ---- phase 1: row max/min (original acc) ----
    // C/D layout: col = lanelo, row = quad*4 + reg  [m89]
#pragma unroll
    for (int rt = 0; rt < 4; ++rt) {
#pragma unroll
        for (int r = 0; r < 4; ++r) {
            const int lrow = wr * 64 + rt * 16 + quad * 4 + r;
            float tmax = NEGF; int targ = 0;
            float tmin = POSF; int targn = 0;
            if (isdiag) {
                const int gi = i0 + lrow;
#pragma unroll
                for (int ct = 0; ct < 4; ++ct) {
                    const int gj = j0 + wc * 64 + ct * 16 + lanelo;
                    const float v = acc[rt][ct][r];
                    const bool dg = (gj == gi);
                    const float vM = dg ? NEGF : v;
                    const float vm = dg ? POSF : v;
                    if (vM > tmax) { tmax = vM; targ = gj; }  // ct asc = j asc
                    if (vm < tmin) { tmin = vm; targn = gj; }
                }
            } else {
#pragma unroll
                for (int ct = 0; ct < 4; ++ct) {
                    const int gj = j0 + wc * 64 + ct * 16 + lanelo;
                    const float v = acc[rt][ct][r];
                    if (v > tmax) { tmax = v; targ = gj; }
                    if (v < tmin) { tmin = v; targn = gj; }
                }
            }
#pragma unroll
            for (int msk = 1; msk < 16; msk <<= 1) {
                const float v2 = __shfl_xor(tmax, msk, 64);
                const int i2 = __shfl_xor(targ, msk, 64);
                if (v2 > tmax) { tmax = v2; targ = i2; }
                const float v3 = __shfl_xor(tmin, msk, 64);
                const int i3 = __shfl_xor(targn, msk, 64);
                if (v3 < tmin) { tmin = v3; targn = i3; }
            }
            if (lanelo == 0) {
                const int o = wc * 128 + lrow;
                rm[o] = tmax; rmn[o] = tmin;
                ra[o] = targ; ran[o] = targn;
            }
        }
    }

    // ---- phase 2: col max/min (strict-upper only, original acc) ----
    if (!isdiag) {
#pragma unroll
        for (int ct = 0; ct < 4; ++ct) {
            const int lcol = wc * 64 + ct * 16 + lanelo;
            float tmax = NEGF; int targ = 0;
            float tmin = POSF; int targn = 0;
#pragma unroll
            for (int rt = 0; rt < 4; ++rt)
#pragma unroll
                for (int r = 0; r < 4; ++r) {
                    const int gi = i0 + wr * 64 + rt * 16 + quad * 4 + r;
                    const float v = acc[rt][ct][r];
                    if (v > tmax) { tmax = v; targ = gi; }  // gi asc in (rt,r)
                    if (v < tmin) { tmin = v; targn = gi; }
                }
#pragma unroll
            for (int msk = 16; msk < 64; msk <<= 1) {
                const float m2 = __shfl_xor(tmax, msk, 64);
                const int i2 = __shfl_xor(targ, msk, 64);
                if (m2 > tmax) { tmax = m2; targ = i2; }
                const float mn2 = __shfl_xor(tmin, msk, 64);
                const int in2 = __shfl_xor(targn, msk, 64);
                if (mn2 < tmin) { tmin = mn2; targn = in2; }
            }
            if (quad == 0) {
                const int o = wr * 128 + lcol;
                cm[o] = tmax; cmn[o] = tmin;
                ca[o] = targ; can[o] = targn;
            }
        }
    }

    // ---- phase 3: acc <- exp(S-1); then zero the 16 diag entries ----
#pragma unroll
    for (int rt = 0; rt < 4; ++rt)
#pragma unroll
        for (int ct = 0; ct < 4; ++ct)
#pragma unroll
            for (int r = 0; r < 4; ++r)
                acc[rt][ct][r] = __expf(acc[rt][ct][r] - 1.f);
    if (isdiag && wr == wc) {
#pragma unroll
        for (int rt = 0; rt < 4; ++rt)
#pragma unroll
            for (int r = 0; r < 4; ++r)
                if (lanelo == quad * 4 + r) acc[rt][rt][r] = 0.f;
    }

    // ---- phase 4: row Zref sums ----
#pragma unroll
    for (int rt = 0; rt < 4; ++rt)
#pragma unroll
        for (int r = 0; r < 4; ++r) {
            float s = acc[rt][0][r] + acc[rt][1][r] +
                      acc[rt][2][r] + acc[rt][3][r];
#pragma unroll
            for (int msk = 1; msk < 16; msk <<= 1) s += __shfl_xor(s, msk, 64);
            if (lanelo == 0)
                rz[wc * 128 + wr * 64 + rt * 16 + quad * 4 + r] = s;
        }

    // ---- phase 5: col Zref sums (strict-upper only) ----
    if (!isdiag) {
#pragma unroll
        for (int ct = 0; ct < 4; ++ct) {
            float s = 0.f;
#pragma unroll
            for (int rt = 0; rt < 4; ++rt)
                s += acc[rt][ct][0] + acc[rt][ct][1] +
                     acc[rt][ct][2] + acc[rt][ct][3];
#pragma unroll
            for (int msk = 16; msk < 64; msk <<= 1) s += __shfl_xor(s, msk, 64);
            if (quad == 0)
                cz[wr * 128 + wc * 64 + ct * 16 + lanelo] = s;
        }
    }

    __syncthreads();

    if (t < BM) {
        // merge row-stat wc-halves (wc0 cols < wc1): row i0+t, slot J
        const float m0 = rm[t], m1 = rm[128 + t];
        float vmax = m0; int imax = ra[t];
        if (m1 > vmax) { vmax = m1; imax = ra[128 + t]; }
        float vmin = rmn[t]; int imin = ran[t];
        if (rmn[128 + t] < vmin) { vmin = rmn[128 + t]; imin = ran[128 + t]; }
        const size_t o = (size_t)J * CDIM + i0 + t;
        pmax[o] = vmax; pmin[o] = vmin; pZ[o] = rz[t] + rz[128 + t];
        pamax[o] = imax; pamin[o] = imin;
    } else if (!isdiag) {
        // merge col-stat wr-halves (wr0 rows < wr1): row j0+tt, slot I
        const int tt = t - BM;
        const float m0 = cm[tt], m1 = cm[128 + tt];
        float vmax = m0; int imax = ca[tt];
        if (m1 > vmax) { vmax = m1; imax = ca[128 + tt]; }
        float vmin = cmn[tt]; int imin = can[tt];
        if (cmn[128 + tt] < vmin) { vmin = cmn[128 + tt]; imin = can[128 + tt]; }
        const size_t o = (size_t)I * CDIM + j0 + tt;
        pmax[o] = vmax; pmin[o] = vmin; pZ[o] = cz[tt] + cz[128 + tt];
        pamax[o] = imax; pamin[o] = imin;
    }
}

// ---- k_lossc: fused partial-merge + triplet distance, one wave per row ----
// lane p owns slot p (cols [p*128,(p+1)*128)); consecutive rows (waves in a
// block) share the same cache lines of each partial array. Butterfly over 64
// lanes merges max/argmax/min/argmin/Z (strict compares: exact cross-slot
// fp32 ties are measure-zero; within-slot order already first-occurrence).
__global__ __launch_bounds__(256) void k_lossc(
    const float* __restrict__ pmax, const float* __restrict__ pmin,
    const float* __restrict__ pZ, const int* __restrict__ pamax,
    const int* __restrict__ pamin, const float* __restrict__ w,
    float* __restrict__ vals) {
    const int wave = threadIdx.x >> 6;
    const int lane = threadIdx.x & 63;
    const int row = blockIdx.x * 4 + wave;
    const size_t o = (size_t)lane * CDIM + row;
    float v = pmax[o]; int a = pamax[o];
    float u = pmin[o]; int b = pamin[o];
    float z = pZ[o];
#pragma unroll
    for (int msk = 1; msk < 64; msk <<= 1) {
        const float v2 = __shfl_xor(v, msk, 64);
        const int i2 = __shfl_xor(a, msk, 64);
        if (v2 > v) { v = v2; a = i2; }
        const float v3 = __shfl_xor(u, msk, 64);
        const int i3 = __shfl_xor(b, msk, 64);
        if (v3 < u) { u = v3; b = i3; }
        z += __shfl_xor(z, msk, 64);
    }
    // P[ms]-P[ls] = (1 - exp(mn-M)) * exp(M-1) / Zref
    const float margin = (1.f - __expf(u - v)) * __expf(v - 1.f) / z;
    const int jm = a, jl = b;

    const float4* wi = (const float4*)(w + (size_t)row * DDIM);
    const float4* wm = (const float4*)(w + (size_t)jm * DDIM);
    const float4* wl = (const float4*)(w + (size_t)jl * DDIM);
    float sm = 0.f, sl = 0.f;
#pragma unroll
    for (int h = 0; h < 2; ++h) {
        const int idx = h * 64 + lane;
        const float4 x = wi[idx];
        const float4 y = wm[idx];
        const float4 c = wl[idx];
        float d;
        d = x.x - y.x; sm = fmaf(d, d, sm);
        d = x.y - y.y; sm = fmaf(d, d, sm);
        d = x.z - y.z; sm = fmaf(d, d, sm);
        d = x.w - y.w; sm = fmaf(d, d, sm);
        d = x.x - c.x; sl = fmaf(d, d, sl);
        d = x.y - c.y; sl = fmaf(d, d, sl);
        d = x.z - c.z; sl = fmaf(d, d, sl);
        d = x.w - c.w; sl = fmaf(d, d, sl);
    }
#pragma unroll
    for (int msk = 1; msk < 64; msk <<= 1) {
        sm += __shfl_xor(sm, msk, 64);
        sl += __shfl_xor(sl, msk, 64);
    }
    if (lane == 0) {
        const float val = sqrtf(sm) - sqrtf(sl) + margin;
        vals[row] = val > 0.f ? val : 0.f;
    }
}

// ---- k_final: deterministic fixed-order mean (no atomics) ----
__global__ __launch_bounds__(256) void k_final(const float* __restrict__ vals,
                                               float* __restrict__ out) {
    __shared__ float red[256];
    float s = 0.f;
    for (int i = threadIdx.x; i < CDIM; i += 256) s += vals[i];
    red[threadIdx.x] = s;
    __syncthreads();
#pragma unroll
    for (int k = 128; k > 0; k >>= 1) {
        if (threadIdx.x < (unsigned)k) red[threadIdx.x] += red[threadIdx.x + k];
        __syncthreads();
    }
    if (threadIdx.x == 0) out[0] = red[0] * (1.0f / CDIM);
}

extern "C" void kernel_launch(void* const* d_in, const int* in_sizes, int n_in,
                              void* d_out, int out_size, void* d_ws, size_t ws_size,
                              hipStream_t stream) {
    const float* g = (const float*)d_in[0];  // gt_class_embeddings [8192,512]
    const float* w = (const float*)d_in[1];  // w [8192,512]
    float* out = (float*)d_out;

    // workspace layout (~26.6 MB)
    unsigned short* ghi = (unsigned short*)d_ws;
    unsigned short* glo = ghi + (size_t)CDIM * DDIM;
    float* p = (float*)(glo + (size_t)CDIM * DDIM);
    float* pmax = p;      p += (size_t)NSLOT * CDIM;
    float* pmin = p;      p += (size_t)NSLOT * CDIM;
    float* pZ = p;        p += (size_t)NSLOT * CDIM;
    int* pamax = (int*)p; p += (size_t)NSLOT * CDIM;
    int* pamin = (int*)p; p += (size_t)NSLOT * CDIM;
    float* vals = p;      p += CDIM;

    k_prep<<<CDIM / 4, 256, 0, stream>>>(g, ghi, glo);
    k_simstats<<<2112, 256, 0, stream>>>(ghi, glo, pmax, pmin, pZ, pamax, pamin);
    k_lossc<<<CDIM / 4, 256, 0, stream>>>(pmax, pmin, pZ, pamax, pamin, w, vals);
    k_final<<<1, 256, 0, stream>>>(vals, out);
}

// Round 13
// 229.500 us; speedup vs baseline: 1.4329x; 1.4329x over previous
//
#include <hip/hip_runtime.h>
#include <math.h>

#define CDIM 8192
#define DDIM 512
#define NEGF -3.0e38f
#define POSF  3.0e38f

#define BM 128
#define NSLOT (CDIM / BM) /* 64 col-slots of 128 per row */

typedef __attribute__((ext_vector_type(8))) short bf16x8;
typedef __attribute__((ext_vector_type(4))) float f32x4;

__device__ __forceinline__ unsigned short f2bf(float x) {
    unsigned int u = __float_as_uint(x);
    u += 0x7fffu + ((u >> 16) & 1u);
    return (unsigned short)(u >> 16);
}
__device__ __forceinline__ float bf2f(unsigned short h) {
    return __uint_as_float(((unsigned int)h) << 16);
}
// async global->LDS, 16B per lane. LDS dest is wave-uniform base + lane*16.
__device__ __forceinline__ void gld16(const void* g, void* l) {
    __builtin_amdgcn_global_load_lds(
        (__attribute__((address_space(1))) void*)(void*)g,
        (__attribute__((address_space(3))) void*)l, 16, 0, 0);
}

// ---- k_prep: normalize rows of G, split into bf16 hi/lo ----
__global__ __launch_bounds__(256) void k_prep(const float* __restrict__ g,
                                              unsigned short* __restrict__ hi,
                                              unsigned short* __restrict__ lo) {
    const int wave = threadIdx.x >> 6;
    const int lane = threadIdx.x & 63;
    const int row = blockIdx.x * 4 + wave;
    const float4* src = (const float4*)(g + (size_t)row * DDIM);
    const float4 a = src[lane * 2];
    const float4 b = src[lane * 2 + 1];
    float s = a.x * a.x + a.y * a.y + a.z * a.z + a.w * a.w +
              b.x * b.x + b.y * b.y + b.z * b.z + b.w * b.w;
#pragma unroll
    for (int m = 1; m < 64; m <<= 1) s += __shfl_xor(s, m, 64);
    const float rn = rsqrtf(s);
    const float y[8] = {a.x * rn, a.y * rn, a.z * rn, a.w * rn,
                        b.x * rn, b.y * rn, b.z * rn, b.w * rn};
    unsigned int hv[4], lv[4];
#pragma unroll
    for (int i = 0; i < 4; ++i) {
        const unsigned short h0 = f2bf(y[2 * i]);
        const unsigned short h1 = f2bf(y[2 * i + 1]);
        const unsigned short l0 = f2bf(y[2 * i] - bf2f(h0));
        const unsigned short l1 = f2bf(y[2 * i + 1] - bf2f(h1));
        hv[i] = (unsigned int)h0 | ((unsigned int)h1 << 16);
        lv[i] = (unsigned int)l0 | ((unsigned int)l1 << 16);
    }
    uint4* dh = (uint4*)(hi + (size_t)row * DDIM + lane * 8);
    uint4* dl = (uint4*)(lo + (size_t)row * DDIM + lane * 8);
    *dh = make_uint4(hv[0], hv[1], hv[2], hv[3]);
    *dl = make_uint4(lv[0], lv[1], lv[2], lv[3]);
}

// Off-diag super-tile assignment table: code = SI*8+SJ (SI<SJ, 8x8 super
// grid over the 64x64 tile grid). XCD0-3: 3 supers each (idx xcd*3+sup);
// XCD4-7: 4 supers each (idx 12+(xcd-4)*4+sup). Greedy-balanced:
// XCD0-3 also carry 2 diagonal supers (36 tiles) -> 264 tiles; XCD4-7: 256.
__device__ __constant__ unsigned char OSUP[28] = {
    1, 2, 10,   3, 11, 19,   4, 12, 20,   28, 5, 13,
    21, 29, 37, 6,   14, 22, 30, 38,   46, 7, 15, 23,   31, 39, 47, 55};

// ---- k_simstats: symmetric, L2 super-tiled, co-staged, BK=32, 32KB LDS ----
// Fixed-reference softmax: Zref = sum exp(S-1) (S in [-1,1] -> exp in
// [.135,1]: no overflow/underflow, partials add plainly).
// 2112 blocks; bid%8 = XCD; each XCD owns whole 8x8 super-tiles (I fastest
// within a super: B-tile shared x8, super's A+B bands L2-resident).
// 128x128 tile, 4 waves 2x2, rt4 x ct4 16x16x32 frags; per K-chunk (BK=32)
// stage Ahi|Alo|Bhi|Blo (32 KB) and run hi*hi+hi*lo+lo*hi.
// launch_bounds (256,3): 170-reg unified budget. (256,4) = 128-reg budget
// SPILLS (R12: WRITE_SIZE 10->332 MB scratch traffic, MfmaUtil 34->18,
// +100 us). acc=64 + arch 64 leaves no headroom at 128. Do not raise.
// Strict-upper tiles also emit col stats (mirror rows, S=S^T). Slot p of row
// i covers cols [p*128,(p+1)*128): row-stats->slot J, col-stats->slot I.
// Cross-lane merges: strict >/< without index tie-break (exact fp32 ties
// across lanes measure-zero; in-lane scan order preserves first-occurrence).
__global__ __launch_bounds__(256, 3) void k_simstats(
    const unsigned short* __restrict__ ghi, const unsigned short* __restrict__ glo,
    float* __restrict__ pmax, float* __restrict__ pmin, float* __restrict__ pZ,
    int* __restrict__ pamax, int* __restrict__ pamin) {
    // ---- tile mapping (block-uniform) ----
    const int bid = blockIdx.x;
    const int xcd = bid & 7;
    const int off = bid >> 3;
    int I, J;
    if (xcd < 4) {
        if (off < 72) {  // two diagonal supers: s = xcd*2 + (off>=36)
            const int s = xcd * 2 + (off >= 36);
            const int u = (off >= 36) ? off - 36 : off;
            int jj = 0;  // triangular: i<=j within the 8x8 super, i fastest
            while ((jj + 1) * (jj + 2) / 2 <= u) ++jj;
            const int ii = u - jj * (jj + 1) / 2;
            I = s * 8 + ii; J = s * 8 + jj;
        } else {
            const int sup = (off - 72) >> 6;
            const int u = (off - 72) & 63;
            const int code = OSUP[xcd * 3 + sup];
            I = (code >> 3) * 8 + (u & 7);   // I fastest: B-tile shared x8
            J = (code & 7) * 8 + (u >> 3);
        }
    } else {
        if (off >= 256) return;  // 32 pad blocks
        const int sup = off >> 6;
        const int u = off & 63;
        const int code = OSUP[12 + (xcd - 4) * 4 + sup];
        I = (code >> 3) * 8 + (u & 7);
        J = (code & 7) * 8 + (u >> 3);
    }

    __shared__ unsigned short SH[4 * BM * 32];  // 32 KB: Ahi|Alo|Bhi|Blo
    unsigned short* Ahi = SH;
    unsigned short* Alo = SH + 4096;
    unsigned short* Bhi = SH + 8192;
    unsigned short* Blo = SH + 12288;
    const int t = threadIdx.x;
    const int wave = t >> 6;
    const int lane = t & 63;
    const int lanelo = lane & 15;
    const int quad = lane >> 4;
    const int wr = wave & 1;
    const int wc = wave >> 1;

    // staging: per region thread t fills slots t*16 + q*4096 ->
    // (row = (t>>2)+64q, chunk-slot = t&3); src chunk = slot ^ ((row>>1)&3)
    const int srow = t >> 2;                             // 0..63
    const int scolb = ((t & 3) ^ ((t >> 3) & 3)) << 4;   // swizzled src chunk
    char* lAh = (char*)Ahi + t * 16;
    char* lAl = (char*)Alo + t * 16;
    char* lBh = (char*)Bhi + t * 16;
    char* lBl = (char*)Blo + t * 16;

    // frag-read slot (ushort units): quad ^ ((lanelo>>1)&3), loop-invariant
    const int fsl = (quad ^ ((lanelo >> 1) & 3)) << 3;
    const int aoff = (wr * 64 + lanelo) * 32 + fsl;  // + rt*16*32
    const int boff = (wc * 64 + lanelo) * 32 + fsl;  // + ct*16*32

    // epilogue LDS overlays (A half: row stats; B half: col stats)
    float* rm  = (float*)SH;            // [2 wc][128]
    float* rz  = rm + 256;
    float* rmn = rz + 256;
    int*   ra  = (int*)(rmn + 256);
    int*   ran = ra + 256;              // 5 KB < 8 KB (Ahi+Alo)
    float* cm  = (float*)Bhi;           // [2 wr][128]
    float* cz  = cm + 256;
    float* cmn = cz + 256;
    int*   ca  = (int*)(cmn + 256);
    int*   can = ca + 256;

    const int i0 = I * BM;
    const int j0 = J * BM;
    const bool isdiag = (I == J);

    f32x4 acc[4][4];
#pragma unroll
    for (int rt = 0; rt < 4; ++rt)
#pragma unroll
        for (int ct = 0; ct < 4; ++ct)
            acc[rt][ct] = (f32x4){0.f, 0.f, 0.f, 0.f};

    const char* baseAh = (const char*)ghi + (size_t)(i0 + srow) * 1024 + scolb;
    const char* baseAl = (const char*)glo + (size_t)(i0 + srow) * 1024 + scolb;
    const char* baseBh = (const char*)ghi + (size_t)(j0 + srow) * 1024 + scolb;
    const char* baseBl = (const char*)glo + (size_t)(j0 + srow) * 1024 + scolb;

    for (int k0 = 0; k0 < DDIM; k0 += 32) {
        __syncthreads();  // prior frag/epilogue LDS reads done
#pragma unroll
        for (int q = 0; q < 2; ++q) {
            const size_t roff = (size_t)q * 64 * 1024 + k0 * 2;
            gld16(baseAh + roff, lAh + q * 4096);
            gld16(baseAl + roff, lAl + q * 4096);
            gld16(baseBh + roff, lBh + q * 4096);
            gld16(baseBl + roff, lBl + q * 4096);
        }
        __syncthreads();  // drains vmcnt: staged data visible
        bf16x8 ah[4], al[4];
#pragma unroll
        for (int rt = 0; rt < 4; ++rt) {
            ah[rt] = *(const bf16x8*)&Ahi[aoff + rt * 512];
            al[rt] = *(const bf16x8*)&Alo[aoff + rt * 512];
        }
#pragma unroll
        for (int ct = 0; ct < 4; ++ct) {
            const bf16x8 bh = *(const bf16x8*)&Bhi[boff + ct * 512];
            const bf16x8 bl = *(const bf16x8*)&Blo[boff + ct * 512];
#pragma unroll
            for (int rt = 0; rt < 4; ++rt) {
                acc[rt][ct] = __builtin_amdgcn_mfma_f32_16x16x32_bf16(
                    ah[rt], bh, acc[rt][ct], 0, 0, 0);
                acc[rt][ct] = __builtin_amdgcn_mfma_f32_16x16x32_bf16(
                    ah[rt], bl, acc[rt][ct], 0, 0, 0);
                acc[rt][ct] = __builtin_amdgcn_mfma_f32_16x16x32_bf16(
                    al[rt], bh, acc[rt][ct], 0, 0, 0);
            }
        }
    }

    __syncthreads();  // all frag reads done before LDS overlay

    // ---- phase 1: row max/min (original acc) ----
    // C/D layout: col = lanelo, row = quad*4 + reg  [m89]
#pragma unroll
    for (int rt = 0; rt < 4; ++rt) {
#pragma unroll
        for (int r = 0; r < 4; ++r) {
            const int lrow = wr * 64 + rt * 16 + quad * 4 + r;
            float tmax = NEGF; int targ = 0;
            float tmin = POSF; int targn = 0;
            if (isdiag) {
                const int gi = i0 + lrow;
#pragma unroll
                for (int ct = 0; ct < 4; ++ct) {
                    const int gj = j0 + wc * 64 + ct * 16 + lanelo;
                    const float v = acc[rt][ct][r];
                    const bool dg = (gj == gi);
                    const float vM = dg ? NEGF : v;
                    const float vm = dg ? POSF : v;
                    if (vM > tmax) { tmax = vM; targ = gj; }  // ct asc = j asc
                    if (vm < tmin) { tmin = vm; targn = gj; }
                }
            } else {
#pragma unroll
                for (int ct = 0; ct < 4; ++ct) {
                    const int gj = j0 + wc * 64 + ct * 16 + lanelo;
                    const float v = acc[rt][ct][r];
                    if (v > tmax) { tmax = v; targ = gj; }
                    if (v < tmin) { tmin = v; targn = gj; }
                }
            }
#pragma unroll
            for (int msk = 1; msk < 16; msk <<= 1) {
                const float v2 = __shfl_xor(tmax, msk, 64);
                const int i2 = __shfl_xor(targ, msk, 64);
                if (v2 > tmax) { tmax = v2; targ = i2; }
                const float v3 = __shfl_xor(tmin, msk, 64);
                const int i3 = __shfl_xor(targn, msk, 64);
                if (v3 < tmin) { tmin = v3; targn = i3; }
            }
            if (lanelo == 0) {
                const int o = wc * 128 + lrow;
                rm[o] = tmax; rmn[o] = tmin;
                ra[o] = targ; ran[o] = targn;
            }
        }
    }

    // ---- phase 2: col max/min (strict-upper only, original acc) ----
    if (!isdiag) {
#pragma unroll
        for (int ct = 0; ct < 4; ++ct) {
            const int lcol = wc * 64 + ct * 16 + lanelo;
            float tmax = NEGF; int targ = 0;
            float tmin = POSF; int targn = 0;
#pragma unroll
            for (int rt = 0; rt < 4; ++rt)
#pragma unroll
                for (int r = 0; r < 4; ++r) {
                    const int gi = i0 + wr * 64 + rt * 16 + quad * 4 + r;
                    const float v = acc[rt][ct][r];
                    if (v > tmax) { tmax = v; targ = gi; }  // gi asc in (rt,r)
                    if (v < tmin) { tmin = v; targn = gi; }
                }
#pragma unroll
            for (int msk = 16; msk < 64; msk <<= 1) {
                const float m2 = __shfl_xor(tmax, msk, 64);
                const int i2 = __shfl_xor(targ, msk, 64);
                if (m2 > tmax) { tmax = m2; targ = i2; }
                const float mn2 = __shfl_xor(tmin, msk, 64);
                const int in2 = __shfl_xor(targn, msk, 64);
                if (mn2 < tmin) { tmin = mn2; targn = in2; }
            }
            if (quad == 0) {
                const int o = wr * 128 + lcol;
                cm[o] = tmax; cmn[o] = tmin;
                ca[o] = targ; can[o] = targn;
            }
        }
    }

    // ---- phase 3: acc <- exp(S-1); then zero the 16 diag entries ----
#pragma unroll
    for (int rt = 0; rt < 4; ++rt)
#pragma unroll
        for (int ct = 0; ct < 4; ++ct)
#pragma unroll
            for (int r = 0; r < 4; ++r)
                acc[rt][ct][r] = __expf(acc[rt][ct][r] - 1.f);
    if (isdiag && wr == wc) {
#pragma unroll
        for (int rt = 0; rt < 4; ++rt)
#pragma unroll
            for (int r = 0; r < 4; ++r)
                if (lanelo == quad * 4 + r) acc[rt][rt][r] = 0.f;
    }

    // ---- phase 4: row Zref sums ----
#pragma unroll
    for (int rt = 0; rt < 4; ++rt)
#pragma unroll
        for (int r = 0; r < 4; ++r) {
            float s = acc[rt][0][r] + acc[rt][1][r] +
                      acc[rt][2][r] + acc[rt][3][r];
#pragma unroll
            for (int msk = 1; msk < 16; msk <<= 1) s += __shfl_xor(s, msk, 64);
            if (lanelo == 0)
                rz[wc * 128 + wr * 64 + rt * 16 + quad * 4 + r] = s;
        }

    // ---- phase 5: col Zref sums (strict-upper only) ----
    if (!isdiag) {
#pragma unroll
        for (int ct = 0; ct < 4; ++ct) {
            float s = 0.f;
#pragma unroll
            for (int rt = 0; rt < 4; ++rt)
                s += acc[rt][ct][0] + acc[rt][ct][1] +
                     acc[rt][ct][2] + acc[rt][ct][3];
#pragma unroll
            for (int msk = 16; msk < 64; msk <<= 1) s += __shfl_xor(s, msk, 64);
            if (quad == 0)
                cz[wr * 128 + wc * 64 + ct * 16 + lanelo] = s;
        }
    }

    __syncthreads();

    if (t < BM) {
        // merge row-stat wc-halves (wc0 cols < wc1): row i0+t, slot J
        const float m0 = rm[t], m1 = rm[128 + t];
        float vmax = m0; int imax = ra[t];
        if (m1 > vmax) { vmax = m1; imax = ra[128 + t]; }
        float vmin = rmn[t]; int imin = ran[t];
        if (rmn[128 + t] < vmin) { vmin = rmn[128 + t]; imin = ran[128 + t]; }
        const size_t o = (size_t)J * CDIM + i0 + t;
        pmax[o] = vmax; pmin[o] = vmin; pZ[o] = rz[t] + rz[128 + t];
        pamax[o] = imax; pamin[o] = imin;
    } else if (!isdiag) {
        // merge col-stat wr-halves (wr0 rows < wr1): row j0+tt, slot I
        const int tt = t - BM;
        const float m0 = cm[tt], m1 = cm[128 + tt];
        float vmax = m0; int imax = ca[tt];
        if (m1 > vmax) { vmax = m1; imax = ca[128 + tt]; }
        float vmin = cmn[tt]; int imin = can[tt];
        if (cmn[128 + tt] < vmin) { vmin = cmn[128 + tt]; imin = can[128 + tt]; }
        const size_t o = (size_t)I * CDIM + j0 + tt;
        pmax[o] = vmax; pmin[o] = vmin; pZ[o] = cz[tt] + cz[128 + tt];
        pamax[o] = imax; pamin[o] = imin;
    }
}

// ---- k_lossc: fused partial-merge + triplet distance, one wave per row ----
// lane p owns slot p (cols [p*128,(p+1)*128)); consecutive rows (waves in a
// block) share the same cache lines of each partial array. Butterfly over 64
// lanes merges max/argmax/min/argmin/Z (strict compares: exact cross-slot
// fp32 ties are measure-zero; within-slot order already first-occurrence).
__global__ __launch_bounds__(256) void k_lossc(
    const float* __restrict__ pmax, const float* __restrict__ pmin,
    const float* __restrict__ pZ, const int* __restrict__ pamax,
    const int* __restrict__ pamin, const float* __restrict__ w,
    float* __restrict__ vals) {
    const int wave = threadIdx.x >> 6;
    const int lane = threadIdx.x & 63;
    const int row = blockIdx.x * 4 + wave;
    const size_t o = (size_t)lane * CDIM + row;
    float v = pmax[o]; int a = pamax[o];
    float u = pmin[o]; int b = pamin[o];
    float z = pZ[o];
#pragma unroll
    for (int msk = 1; msk < 64; msk <<= 1) {
        const float v2 = __shfl_xor(v, msk, 64);
        const int i2 = __shfl_xor(a, msk, 64);
        if (v2 > v) { v = v2; a = i2; }
        const float v3 = __shfl_xor(u, msk, 64);
        const int i3 = __shfl_xor(b, msk, 64);
        if (v3 < u) { u = v3; b = i3; }
        z += __shfl_xor(z, msk, 64);
    }
    // P[ms]-P[ls] = (1 - exp(mn-M)) * exp(M-1) / Zref
    const float margin = (1.f - __expf(u - v)) * __expf(v - 1.f) / z;
    const int jm = a, jl = b;

    const float4* wi = (const float4*)(w + (size_t)row * DDIM);
    const float4* wm = (const float4*)(w + (size_t)jm * DDIM);
    const float4* wl = (const float4*)(w + (size_t)jl * DDIM);
    float sm = 0.f, sl = 0.f;
#pragma unroll
    for (int h = 0; h < 2; ++h) {
        const int idx = h * 64 + lane;
        const float4 x = wi[idx];
        const float4 y = wm[idx];
        const float4 c = wl[idx];
        float d;
        d = x.x - y.x; sm = fmaf(d, d, sm);
        d = x.y - y.y; sm = fmaf(d, d, sm);
        d = x.z - y.z; sm = fmaf(d, d, sm);
        d = x.w - y.w; sm = fmaf(d, d, sm);
        d = x.x - c.x; sl = fmaf(d, d, sl);
        d = x.y - c.y; sl = fmaf(d, d, sl);
        d = x.z - c.z; sl = fmaf(d, d, sl);
        d = x.w - c.w; sl = fmaf(d, d, sl);
    }
#pragma unroll
    for (int msk = 1; msk < 64; msk <<= 1) {
        sm += __shfl_xor(sm, msk, 64);
        sl += __shfl_xor(sl, msk, 64);
    }
    if (lane == 0) {
        const float val = sqrtf(sm) - sqrtf(sl) + margin;
        vals[row] = val > 0.f ? val : 0.f;
    }
}

// ---- k_final: deterministic fixed-order mean (no atomics) ----
__global__ __launch_bounds__(256) void k_final(const float* __restrict__ vals,
                                               float* __restrict__ out) {
    __shared__ float red[256];
    float s = 0.f;
    for (int i = threadIdx.x; i < CDIM; i += 256) s += vals[i];
    red[threadIdx.x] = s;
    __syncthreads();
#pragma unroll
    for (int k = 128; k > 0; k >>= 1) {
        if (threadIdx.x < (unsigned)k) red[threadIdx.x] += red[threadIdx.x + k];
        __syncthreads();
    }
    if (threadIdx.x == 0) out[0] = red[0] * (1.0f / CDIM);
}

extern "C" void kernel_launch(void* const* d_in, const int* in_sizes, int n_in,
                              void* d_out, int out_size, void* d_ws, size_t ws_size,
                              hipStream_t stream) {
    const float* g = (const float*)d_in[0];  // gt_class_embeddings [8192,512]
    const float* w = (const float*)d_in[1];  // w [8192,512]
    float* out = (float*)d_out;

    // workspace layout (~26.6 MB)
    unsigned short* ghi = (unsigned short*)d_ws;
    unsigned short* glo = ghi + (size_t)CDIM * DDIM;
    float* p = (float*)(glo + (size_t)CDIM * DDIM);
    float* pmax = p;      p += (size_t)NSLOT * CDIM;
    float* pmin = p;      p += (size_t)NSLOT * CDIM;
    float* pZ = p;        p += (size_t)NSLOT * CDIM;
    int* pamax = (int*)p; p += (size_t)NSLOT * CDIM;
    int* pamin = (int*)p; p += (size_t)NSLOT * CDIM;
    float* vals = p;      p += CDIM;

    k_prep<<<CDIM / 4, 256, 0, stream>>>(g, ghi, glo);
    k_simstats<<<2112, 256, 0, stream>>>(ghi, glo, pmax, pmin, pZ, pamax, pamin);
    k_lossc<<<CDIM / 4, 256, 0, stream>>>(pmax, pmin, pZ, pamax, pamin, w, vals);
    k_final<<<1, 256, 0, stream>>>(vals, out);
}